// Round 1
// baseline (2422.564 us; speedup 1.0000x reference)
//
#include <hip/hip_runtime.h>
#include <hip/hip_bf16.h>

// Swin block: B=32 H=W=56 C=512 NH=16 HD=32 WS=7 N=49 nW=64 Bn=2048 HID=2048
// External tensors may be fp32 OR bf16 -> runtime flag detected from norm1_g
// (exact ones: first word 0x3F800000 => fp32, 0x3F803F80 => bf16).
// Internal compute: bf16 MFMA GEMMs (16x16x32) with fp32 accumulate.

typedef unsigned short u16;
typedef __bf16 bf16x8 __attribute__((ext_vector_type(8)));
typedef float floatx4 __attribute__((ext_vector_type(4)));

#define MROWS 100352   // B*H*W = Bn*N
#define SCALE_ATTN 0.17677669529663687f

__device__ __forceinline__ float b2f(u16 u) {
    union { unsigned int i; float f; } c; c.i = ((unsigned int)u) << 16; return c.f;
}
__device__ __forceinline__ u16 f2b(float f) {
    union { float f; unsigned int u; } c; c.f = f;
    unsigned int r = c.u + 0x7fffu + ((c.u >> 16) & 1u);
    return (u16)(r >> 16);
}

// token index for (win, n) after roll(-3,-3) + window partition.
__device__ __forceinline__ int win_token(int win, int n) {
    int b  = win >> 6;
    int wi = (win & 63) >> 3;
    int wj = win & 7;
    int ti = n / 7;
    int tj = n - ti * 7;
    int ii = wi * 7 + ti + 3; if (ii >= 56) ii -= 56;
    int jj = wj * 7 + tj + 3; if (jj >= 56) jj -= 56;
    return b * 3136 + ii * 56 + jj;
}

// ---------------- dtype flag: 1 if external tensors are fp32 ----------------
__global__ void detect_flag(const unsigned int* __restrict__ g1, int* __restrict__ flag) {
    if (threadIdx.x == 0 && blockIdx.x == 0)
        *flag = (g1[0] == 0x3F800000u) ? 1 : 0;
}

// ---------------- external -> fp32 convert ----------------------------------
__global__ __launch_bounds__(256)
void conv_f32(const void* __restrict__ src, float* __restrict__ dst, int n,
              const int* __restrict__ flag) {
    int i = blockIdx.x * 256 + threadIdx.x;
    if (i >= n) return;
    if (*flag) dst[i] = ((const float*)src)[i];
    else       dst[i] = b2f(((const u16*)src)[i]);
}

// ---------------- weight transpose (src R x Cc -> dst bf16 Cc x R) ----------
__global__ __launch_bounds__(256)
void transpose_k(const void* __restrict__ srcv, u16* __restrict__ dst, int R, int Cc,
                 const int* __restrict__ flag) {
    const bool f32 = (*flag != 0);
    __shared__ u16 tile[32][33];
    int tx = threadIdx.x & 31, ty = threadIdx.x >> 5;
    int c0 = blockIdx.x << 5, r0 = blockIdx.y << 5;
#pragma unroll
    for (int j = 0; j < 4; ++j) {
        size_t idx = (size_t)(r0 + ty + j * 8) * Cc + c0 + tx;
        tile[ty + j * 8][tx] = f32 ? f2b(((const float*)srcv)[idx]) : ((const u16*)srcv)[idx];
    }
    __syncthreads();
#pragma unroll
    for (int j = 0; j < 4; ++j)
        dst[(size_t)(c0 + ty + j * 8) * R + r0 + tx] = tile[tx][ty + j * 8];
}

// ---------------- relative-position bias expand: biasf[head][n][m] fp32 -----
__global__ __launch_bounds__(256)
void bias_expand(const float* __restrict__ tblf, const int* __restrict__ ridx,
                 float* __restrict__ biasf) {
    int i = blockIdx.x * 256 + threadIdx.x;
    if (i < 16 * 2401) {
        int head = i / 2401, r = i - head * 2401;
        biasf[i] = tblf[ridx[r] * 16 + head];
    }
}

// ---------------- LayerNorm (block per row, 256 thr, 2 ch/thr) --------------
// REMAP (LN1): src is EXTERNAL (flag dtype), output row gathers rolled token.
// !REMAP (LN2): src is internal bf16, identity rows.
template <bool REMAP>
__global__ __launch_bounds__(256)
void ln_kernel(const void* __restrict__ srcv, const float* __restrict__ g,
               const float* __restrict__ bb, u16* __restrict__ dst,
               const int* __restrict__ flag) {
    int row = blockIdx.x;
    size_t srow;
    if (REMAP) {
        int win = row / 49, n = row - win * 49;
        srow = (size_t)win_token(win, n);
    } else {
        srow = (size_t)row;
    }
    int t = threadIdx.x;
    float v0, v1;
    if (REMAP && *flag) {
        float2 u = *(const float2*)((const float*)srcv + srow * 512 + t * 2);
        v0 = u.x; v1 = u.y;
    } else {
        ushort2 u = *(const ushort2*)((const u16*)srcv + srow * 512 + t * 2);
        v0 = b2f(u.x); v1 = b2f(u.y);
    }
    float sum = v0 + v1, sq = v0 * v0 + v1 * v1;
#pragma unroll
    for (int off = 32; off > 0; off >>= 1) {
        sum += __shfl_down(sum, off);
        sq  += __shfl_down(sq, off);
    }
    __shared__ float s1[4], s2[4];
    int wv = t >> 6, ln = t & 63;
    if (ln == 0) { s1[wv] = sum; s2[wv] = sq; }
    __syncthreads();
    float tot  = s1[0] + s1[1] + s1[2] + s1[3];
    float tot2 = s2[0] + s2[1] + s2[2] + s2[3];
    float mean = tot * (1.0f / 512.0f);
    float var  = tot2 * (1.0f / 512.0f) - mean * mean;
    float rstd = rsqrtf(var + 1e-5f);
    float o0 = (v0 - mean) * rstd * g[t * 2]     + bb[t * 2];
    float o1 = (v1 - mean) * rstd * g[t * 2 + 1] + bb[t * 2 + 1];
    ushort2 ou; ou.x = f2b(o0); ou.y = f2b(o1);
    *(ushort2*)(dst + (size_t)row * 512 + t * 2) = ou;
}

// ---------------- 128x128 bf16 MFMA GEMM, C = A(MxK) * Bt(NxK)^T + bias -----
// m97 structure: async global_load_lds (dwordx4) staging into LINEAR LDS
// [128][32] u16 (no pad -- global_load_lds writes base + lane*16), 2-barrier
// K-loop, 4x4 16x16x32 MFMA per wave.
// MODE 0: bf16 out (internal). MODE 1: GELU(exact) bf16 out (internal).
// MODE 2: window-reverse scatter + EXTERNAL residual -> bf16 out (internal).
// MODE 3: + internal bf16 residual (chunk-local rows) -> EXTERNAL-dtype out
//         at absolute rows (row + row_off).
template <int MODE>
__global__ __launch_bounds__(256)
void gemm128(const u16* __restrict__ A, const u16* __restrict__ Bt,
             const float* __restrict__ bias, int K, int Nn,
             void* __restrict__ outv, const void* __restrict__ resv,
             const int* __restrict__ flag, int row_off) {
    __shared__ __align__(16) u16 As[128 * 32];
    __shared__ __align__(16) u16 Bs[128 * 32];
    const int tid = threadIdx.x;
    const int bm = blockIdx.x, bn = blockIdx.y;
    const int wave = tid >> 6, lane = tid & 63;
    const int wr = (wave >> 1) << 6, wc = (wave & 1) << 6;
    const int lm = lane & 15, lq = lane >> 4;

    floatx4 acc[4][4];
#pragma unroll
    for (int i = 0; i < 4; ++i)
#pragma unroll
        for (int j = 0; j < 4; ++j)
            acc[i][j] = (floatx4){0.f, 0.f, 0.f, 0.f};

    const size_t arow0 = (size_t)bm * 128;
    const size_t brow0 = (size_t)bn * 128;

    // Staging geometry: A-tile (128 rows x 32 u16 cols = 8 KiB) is 8 chunks of
    // 1 KiB (16 rows each). Wave w stages chunks {2w, 2w+1} of A and of B.
    // Within a chunk, lane l covers row 16c + (l>>2), bytes (l&3)*16 of the
    // 64-byte row slice -> LDS dest = chunk_base + l*16 (linear, HW layout).
    const int c0 = wave << 1;
    const int rA = (c0 << 4) + (lane >> 2);
    const int kc = (lane & 3) << 3;                 // u16 offset in 32-col slice
    const u16* gA0 = A  + (arow0 + rA) * K + kc;
    const u16* gA1 = gA0 + (size_t)16 * K;
    const u16* gB0 = Bt + (brow0 + rA) * K + kc;
    const u16* gB1 = gB0 + (size_t)16 * K;
    u16* lA0 = As + (c0 << 9);                      // c0*512 u16 = c0*1024 B
    u16* lA1 = lA0 + 512;
    u16* lB0 = Bs + (c0 << 9);
    u16* lB1 = lB0 + 512;

    for (int k0 = 0; k0 < K; k0 += 32) {
        __builtin_amdgcn_global_load_lds(
            (const __attribute__((address_space(1))) void*)(gA0 + k0),
            (__attribute__((address_space(3))) void*)lA0, 16, 0, 0);
        __builtin_amdgcn_global_load_lds(
            (const __attribute__((address_space(1))) void*)(gA1 + k0),
            (__attribute__((address_space(3))) void*)lA1, 16, 0, 0);
        __builtin_amdgcn_global_load_lds(
            (const __attribute__((address_space(1))) void*)(gB0 + k0),
            (__attribute__((address_space(3))) void*)lB0, 16, 0, 0);
        __builtin_amdgcn_global_load_lds(
            (const __attribute__((address_space(1))) void*)(gB1 + k0),
            (__attribute__((address_space(3))) void*)lB1, 16, 0, 0);
        __syncthreads();   // compiler emits vmcnt(0) drain before s_barrier
        bf16x8 af[4], bf[4];
#pragma unroll
        for (int i = 0; i < 4; ++i)
            af[i] = *(const bf16x8*)(&As[(wr + (i << 4) + lm) * 32 + (lq << 3)]);
#pragma unroll
        for (int j = 0; j < 4; ++j)
            bf[j] = *(const bf16x8*)(&Bs[(wc + (j << 4) + lm) * 32 + (lq << 3)]);
#pragma unroll
        for (int i = 0; i < 4; ++i)
#pragma unroll
            for (int j = 0; j < 4; ++j)
                acc[i][j] = __builtin_amdgcn_mfma_f32_16x16x32_bf16(af[i], bf[j], acc[i][j], 0, 0, 0);
        __syncthreads();   // all waves done reading before next overwrite
    }

    const bool f32 = (MODE >= 2) ? (*flag != 0) : false;
#pragma unroll
    for (int i = 0; i < 4; ++i) {
#pragma unroll
        for (int r = 0; r < 4; ++r) {
            const int row = (bm << 7) + wr + (i << 4) + (lq << 2) + r;
            size_t orow;
            if (MODE == 2) {
                int win = row / 49, n = row - win * 49;
                orow = (size_t)win_token(win, n);
            } else {
                orow = (size_t)row;
            }
#pragma unroll
            for (int j = 0; j < 4; ++j) {
                const int col = (bn << 7) + wc + (j << 4) + lm;
                float v = acc[i][j][r] + bias[col];
                if (MODE == 0) {
                    ((u16*)outv)[(size_t)row * Nn + col] = f2b(v);
                } else if (MODE == 1) {
                    v = 0.5f * v * (1.0f + erff(v * 0.70710678118654752f));
                    ((u16*)outv)[(size_t)row * Nn + col] = f2b(v);
                } else if (MODE == 2) {
                    float res = f32 ? ((const float*)resv)[orow * 512 + col]
                                    : b2f(((const u16*)resv)[orow * 512 + col]);
                    ((u16*)outv)[orow * 512 + col] = f2b(v + res);
                } else {
                    float res = b2f(((const u16*)resv)[(size_t)row * Nn + col]);
                    size_t grow = (size_t)(row + row_off);
                    if (f32) ((float*)outv)[grow * Nn + col] = v + res;
                    else     ((u16*)outv)[grow * Nn + col]  = f2b(v + res);
                }
            }
        }
    }
}

// ---------------- attention: one wave per (window, head) --------------------
__global__ __launch_bounds__(64)
void attn_kernel(const u16* __restrict__ qkv, const float* __restrict__ biasf,
                 const float* __restrict__ amaskf, u16* __restrict__ o, int win_base) {
    const int blk = blockIdx.x;
    const int winl = blk >> 4, head = blk & 15;
    const int wing = win_base + winl;
    const int w = wing & 63;
    const int t = threadIdx.x;
    __shared__ float qf[49 * 32], kf[49 * 32], vf[49 * 32];
    const size_t base = (size_t)winl * 49 * 1536 + head * 32;
    for (int idx = t; idx < 392; idx += 64) {
        int m = idx >> 3, d = (idx & 7) << 2;
        size_t rb = base + (size_t)m * 1536 + d;
        ushort4 uq = *(const ushort4*)(qkv + rb);
        ushort4 uk = *(const ushort4*)(qkv + rb + 512);
        ushort4 uv = *(const ushort4*)(qkv + rb + 1024);
        int o4 = m * 32 + d;
        qf[o4 + 0] = b2f(uq.x); qf[o4 + 1] = b2f(uq.y);
        qf[o4 + 2] = b2f(uq.z); qf[o4 + 3] = b2f(uq.w);
        kf[o4 + 0] = b2f(uk.x); kf[o4 + 1] = b2f(uk.y);
        kf[o4 + 2] = b2f(uk.z); kf[o4 + 3] = b2f(uk.w);
        vf[o4 + 0] = b2f(uv.x); vf[o4 + 1] = b2f(uv.y);
        vf[o4 + 2] = b2f(uv.z); vf[o4 + 3] = b2f(uv.w);
    }
    __syncthreads();
    if (t < 49) {
        float q[32];
#pragma unroll
        for (int d = 0; d < 32; ++d) q[d] = qf[t * 32 + d] * SCALE_ATTN;
        float s[49];
        float mx = -1e30f;
        const float* bp = biasf + head * 2401 + t * 49;
        const float* mp = amaskf + w * 2401 + t * 49;
#pragma unroll
        for (int m = 0; m < 49; ++m) {
            float acc = 0.f;
#pragma unroll
            for (int d = 0; d < 32; ++d) acc += q[d] * kf[m * 32 + d];
            acc += bp[m] + mp[m];
            s[m] = acc;
            mx = fmaxf(mx, acc);
        }
        float sum = 0.f;
#pragma unroll
        for (int m = 0; m < 49; ++m) { s[m] = __expf(s[m] - mx); sum += s[m]; }
        float inv = 1.0f / sum;
        float ov[32];
#pragma unroll
        for (int d = 0; d < 32; ++d) ov[d] = 0.f;
#pragma unroll
        for (int m = 0; m < 49; ++m) {
            float p = s[m];
#pragma unroll
            for (int d = 0; d < 32; ++d) ov[d] += p * vf[m * 32 + d];
        }
        u16* op = o + (size_t)(wing * 49 + t) * 512 + head * 32;
#pragma unroll
        for (int dc = 0; dc < 32; dc += 4) {
            ushort4 pk;
            pk.x = f2b(ov[dc + 0] * inv); pk.y = f2b(ov[dc + 1] * inv);
            pk.z = f2b(ov[dc + 2] * inv); pk.w = f2b(ov[dc + 3] * inv);
            *(ushort4*)(op + dc) = pk;
        }
    }
}

extern "C" void kernel_launch(void* const* d_in, const int* in_sizes, int n_in,
                              void* d_out, int out_size, void* d_ws, size_t ws_size,
                              hipStream_t stream) {
    const void* x      = d_in[0];
    const void* n1g    = d_in[1];
    const void* n1b    = d_in[2];
    const void* qkv_w  = d_in[3];
    const void* qkv_b  = d_in[4];
    const void* relt   = d_in[5];
    const void* proj_w = d_in[6];
    const void* proj_b = d_in[7];
    const void* n2g    = d_in[8];
    const void* n2b    = d_in[9];
    const void* fc1_w  = d_in[10];
    const void* fc1_b  = d_in[11];
    const void* fc2_w  = d_in[12];
    const void* fc2_b  = d_in[13];
    const int*  ridx   = (const int*)d_in[14];
    const void* amask  = d_in[15];

    char* ws = (char*)d_ws;
    u16*  wT_qkv  = (u16*)(ws);                       // 1536x512 bf16
    u16*  wT_proj = (u16*)(ws + 1572864);             // 512x512
    u16*  wT_fc1  = (u16*)(ws + 2097152);             // 2048x512
    u16*  wT_fc2  = (u16*)(ws + 4194304);             // 512x2048 -> ends 6,291,456
    float* biasf  = (float*)(ws + 6291456);           // 16*2401 -> ends 6,445,120
    float* amaskf = (float*)(ws + 6445120);           // 64*2401 -> ends 7,059,776
    float* qkv_bf = (float*)(ws + 7059776);           // 1536
    float* proj_bf= (float*)(ws + 7065920);           // 512
    float* fc1_bf = (float*)(ws + 7067968);           // 2048
    float* fc2_bf = (float*)(ws + 7076160);           // 512
    float* n1gf   = (float*)(ws + 7078208);           // 512
    float* n1bf   = (float*)(ws + 7080256);           // 512
    float* n2gf   = (float*)(ws + 7082304);           // 512
    float* n2bf   = (float*)(ws + 7084352);           // 512
    float* reltf  = (float*)(ws + 7086400);           // 169*16 -> ends 7,097,216
    int*   flag   = (int*)(ws + 7097216);
    u16* bufA = (u16*)(ws + 8388608);                 // 102,760,448 B : wins -> y
    u16* bufB = (u16*)(ws + 8388608 + 102760448);     //  77,070,336 B : qkv chunk -> m1 chunk
    u16* bufC = (u16*)(ws + 8388608 + 102760448 + 77070336); // 102,760,448 B : o -> h2
    // peak ws usage = 290,979,840 B

    detect_flag<<<1, 64, 0, stream>>>((const unsigned int*)n1g, flag);

    conv_f32<<<6, 256, 0, stream>>>(qkv_b, qkv_bf, 1536, flag);
    conv_f32<<<2, 256, 0, stream>>>(proj_b, proj_bf, 512, flag);
    conv_f32<<<8, 256, 0, stream>>>(fc1_b, fc1_bf, 2048, flag);
    conv_f32<<<2, 256, 0, stream>>>(fc2_b, fc2_bf, 512, flag);
    conv_f32<<<2, 256, 0, stream>>>(n1g, n1gf, 512, flag);
    conv_f32<<<2, 256, 0, stream>>>(n1b, n1bf, 512, flag);
    conv_f32<<<2, 256, 0, stream>>>(n2g, n2gf, 512, flag);
    conv_f32<<<2, 256, 0, stream>>>(n2b, n2bf, 512, flag);
    conv_f32<<<11, 256, 0, stream>>>(relt, reltf, 169 * 16, flag);
    conv_f32<<<(64 * 2401 + 255) / 256, 256, 0, stream>>>(amask, amaskf, 64 * 2401, flag);

    transpose_k<<<dim3(48, 16), 256, 0, stream>>>(qkv_w, wT_qkv, 512, 1536, flag);
    transpose_k<<<dim3(16, 16), 256, 0, stream>>>(proj_w, wT_proj, 512, 512, flag);
    transpose_k<<<dim3(64, 16), 256, 0, stream>>>(fc1_w, wT_fc1, 512, 2048, flag);
    transpose_k<<<dim3(16, 64), 256, 0, stream>>>(fc2_w, wT_fc2, 2048, 512, flag);
    bias_expand<<<(16 * 2401 + 255) / 256, 256, 0, stream>>>(reltf, ridx, biasf);

    // LN1 + roll + window partition -> wins (bufA)
    ln_kernel<true><<<MROWS, 256, 0, stream>>>(x, n1gf, n1bf, bufA, flag);

    // QKV + attention in 4 window-chunks of 512 windows (25088 rows)
    for (int c = 0; c < 4; ++c) {
        const u16* Ain = bufA + (size_t)c * 25088 * 512;
        gemm128<0><<<dim3(196, 12), 256, 0, stream>>>(Ain, wT_qkv, qkv_bf, 512, 1536, bufB, nullptr, flag, 0);
        attn_kernel<<<512 * 16, 64, 0, stream>>>(bufB, biasf, amaskf, bufC, c * 512);
    }

    // proj + window reverse + roll + x residual -> y (bufA, bf16)
    gemm128<2><<<dim3(784, 4), 256, 0, stream>>>(bufC, wT_proj, proj_bf, 512, 512, bufA, x, flag, 0);

    // LN2 -> h2 (bufC)
    ln_kernel<false><<<MROWS, 256, 0, stream>>>(bufA, n2gf, n2bf, bufC, flag);

    // MLP in row-chunks of 16384 (m1 chunk in bufB: 16384*2048*2 = 67.1 MB)
    for (int mc0 = 0; mc0 < MROWS; mc0 += 16384) {
        int rows = (MROWS - mc0 < 16384) ? (MROWS - mc0) : 16384;
        int tiles = rows >> 7;
        gemm128<1><<<dim3(tiles, 16), 256, 0, stream>>>(bufC + (size_t)mc0 * 512, wT_fc1, fc1_bf, 512, 2048, bufB, nullptr, flag, 0);
        gemm128<3><<<dim3(tiles, 4), 256, 0, stream>>>(bufB, wT_fc2, fc2_bf, 2048, 512, d_out, bufA + (size_t)mc0 * 512, flag, mc0);
    }
}

// Round 2
// 2328.189 us; speedup vs baseline: 1.0405x; 1.0405x over previous
//
#include <hip/hip_runtime.h>
#include <hip/hip_bf16.h>

// Swin block: B=32 H=W=56 C=512 NH=16 HD=32 WS=7 N=49 nW=64 Bn=2048 HID=2048
// External tensors may be fp32 OR bf16 -> runtime flag detected from norm1_g
// (exact ones: first word 0x3F800000 => fp32, 0x3F803F80 => bf16).
// Internal compute: bf16 MFMA GEMMs (16x16x32) with fp32 accumulate.

typedef unsigned short u16;
typedef __bf16 bf16x8 __attribute__((ext_vector_type(8)));
typedef float floatx4 __attribute__((ext_vector_type(4)));

#define MROWS 100352   // B*H*W = Bn*N
#define SCALE_ATTN 0.17677669529663687f

__device__ __forceinline__ float b2f(u16 u) {
    union { unsigned int i; float f; } c; c.i = ((unsigned int)u) << 16; return c.f;
}
__device__ __forceinline__ u16 f2b(float f) {
    union { float f; unsigned int u; } c; c.f = f;
    unsigned int r = c.u + 0x7fffu + ((c.u >> 16) & 1u);
    return (u16)(r >> 16);
}

// token index for (win, n) after roll(-3,-3) + window partition.
__device__ __forceinline__ int win_token(int win, int n) {
    int b  = win >> 6;
    int wi = (win & 63) >> 3;
    int wj = win & 7;
    int ti = n / 7;
    int tj = n - ti * 7;
    int ii = wi * 7 + ti + 3; if (ii >= 56) ii -= 56;
    int jj = wj * 7 + tj + 3; if (jj >= 56) jj -= 56;
    return b * 3136 + ii * 56 + jj;
}

// async global->LDS, 16B per lane, linear dest (base + lane*16)
#define GL2LDS(gaddr, laddr) \
    __builtin_amdgcn_global_load_lds((const __attribute__((address_space(1))) void*)(gaddr), \
                                     (__attribute__((address_space(3))) void*)(laddr), 16, 0, 0)

// ---------------- dtype flag: 1 if external tensors are fp32 ----------------
__global__ void detect_flag(const unsigned int* __restrict__ g1, int* __restrict__ flag) {
    if (threadIdx.x == 0 && blockIdx.x == 0)
        *flag = (g1[0] == 0x3F800000u) ? 1 : 0;
}

// ---------------- external -> fp32 convert ----------------------------------
__global__ __launch_bounds__(256)
void conv_f32(const void* __restrict__ src, float* __restrict__ dst, int n,
              const int* __restrict__ flag) {
    int i = blockIdx.x * 256 + threadIdx.x;
    if (i >= n) return;
    if (*flag) dst[i] = ((const float*)src)[i];
    else       dst[i] = b2f(((const u16*)src)[i]);
}

// ---------------- weight transpose (src R x Cc -> dst bf16 Cc x R) ----------
__global__ __launch_bounds__(256)
void transpose_k(const void* __restrict__ srcv, u16* __restrict__ dst, int R, int Cc,
                 const int* __restrict__ flag) {
    const bool f32 = (*flag != 0);
    __shared__ u16 tile[32][33];
    int tx = threadIdx.x & 31, ty = threadIdx.x >> 5;
    int c0 = blockIdx.x << 5, r0 = blockIdx.y << 5;
#pragma unroll
    for (int j = 0; j < 4; ++j) {
        size_t idx = (size_t)(r0 + ty + j * 8) * Cc + c0 + tx;
        tile[ty + j * 8][tx] = f32 ? f2b(((const float*)srcv)[idx]) : ((const u16*)srcv)[idx];
    }
    __syncthreads();
#pragma unroll
    for (int j = 0; j < 4; ++j)
        dst[(size_t)(c0 + ty + j * 8) * R + r0 + tx] = tile[tx][ty + j * 8];
}

// ---------------- relative-position bias expand: biasf[head][n][m] fp32 -----
__global__ __launch_bounds__(256)
void bias_expand(const float* __restrict__ tblf, const int* __restrict__ ridx,
                 float* __restrict__ biasf) {
    int i = blockIdx.x * 256 + threadIdx.x;
    if (i < 16 * 2401) {
        int head = i / 2401, r = i - head * 2401;
        biasf[i] = tblf[ridx[r] * 16 + head];
    }
}

// ---------------- LayerNorm (block per row, 256 thr, 2 ch/thr) --------------
template <bool REMAP>
__global__ __launch_bounds__(256)
void ln_kernel(const void* __restrict__ srcv, const float* __restrict__ g,
               const float* __restrict__ bb, u16* __restrict__ dst,
               const int* __restrict__ flag) {
    int row = blockIdx.x;
    size_t srow;
    if (REMAP) {
        int win = row / 49, n = row - win * 49;
        srow = (size_t)win_token(win, n);
    } else {
        srow = (size_t)row;
    }
    int t = threadIdx.x;
    float v0, v1;
    if (REMAP && *flag) {
        float2 u = *(const float2*)((const float*)srcv + srow * 512 + t * 2);
        v0 = u.x; v1 = u.y;
    } else {
        ushort2 u = *(const ushort2*)((const u16*)srcv + srow * 512 + t * 2);
        v0 = b2f(u.x); v1 = b2f(u.y);
    }
    float sum = v0 + v1, sq = v0 * v0 + v1 * v1;
#pragma unroll
    for (int off = 32; off > 0; off >>= 1) {
        sum += __shfl_down(sum, off);
        sq  += __shfl_down(sq, off);
    }
    __shared__ float s1[4], s2[4];
    int wv = t >> 6, ln = t & 63;
    if (ln == 0) { s1[wv] = sum; s2[wv] = sq; }
    __syncthreads();
    float tot  = s1[0] + s1[1] + s1[2] + s1[3];
    float tot2 = s2[0] + s2[1] + s2[2] + s2[3];
    float mean = tot * (1.0f / 512.0f);
    float var  = tot2 * (1.0f / 512.0f) - mean * mean;
    float rstd = rsqrtf(var + 1e-5f);
    float o0 = (v0 - mean) * rstd * g[t * 2]     + bb[t * 2];
    float o1 = (v1 - mean) * rstd * g[t * 2 + 1] + bb[t * 2 + 1];
    ushort2 ou; ou.x = f2b(o0); ou.y = f2b(o1);
    *(ushort2*)(dst + (size_t)row * 512 + t * 2) = ou;
}

// ---------------- 128x128 bf16 MFMA GEMM, C = A(MxK) * Bt(NxK)^T + bias -----
// 1-D grid, bijective XCD-chunk swizzle (m204) + bn-fastest decomposition so
// each XCD's L2 sees each A-panel's nbn consumers back-to-back (A fetched ~1x).
// Double-buffered async staging (T3 minimum 2-phase): issue next K-tile's
// global_load_lds BEFORE compute of current tile; single barrier per K-step
// (its vmcnt(0) drain lands after the compute phase -> latency overlapped).
// MODE 0: bf16 out. MODE 1: GELU(exact) bf16 out. MODE 2: window-reverse
// scatter + EXTERNAL residual -> bf16 out. MODE 3: + internal bf16 residual
// (chunk-local rows) -> EXTERNAL-dtype out at absolute rows (row + row_off).
template <int MODE>
__global__ __launch_bounds__(256)
void gemm128(const u16* __restrict__ A, const u16* __restrict__ Bt,
             const float* __restrict__ bias, int K, int Nn, int nbn,
             void* __restrict__ outv, const void* __restrict__ resv,
             const int* __restrict__ flag, int row_off) {
    __shared__ __align__(16) u16 As[2 * 128 * 32];
    __shared__ __align__(16) u16 Bs[2 * 128 * 32];
    const int tid = threadIdx.x;

    // bijective XCD remap: contiguous logical ids land on one XCD
    const int nwg = (int)gridDim.x;
    const int bid = (int)blockIdx.x;
    const int q = nwg >> 3, r = nwg & 7;
    const int xcd = bid & 7, idx = bid >> 3;
    const int base = (xcd < r) ? xcd * (q + 1) : r * (q + 1) + (xcd - r) * q;
    const int wg = base + idx;
    const int bm = wg / nbn;
    const int bn = wg - bm * nbn;

    const int wave = tid >> 6, lane = tid & 63;
    const int wr = (wave >> 1) << 6, wc = (wave & 1) << 6;
    const int lm = lane & 15, lq = lane >> 4;

    floatx4 acc[4][4];
#pragma unroll
    for (int i = 0; i < 4; ++i)
#pragma unroll
        for (int j = 0; j < 4; ++j)
            acc[i][j] = (floatx4){0.f, 0.f, 0.f, 0.f};

    const size_t arow0 = (size_t)bm * 128;
    const size_t brow0 = (size_t)bn * 128;

    // Staging geometry: per K-step a 128x32 u16 tile (8 KiB) = 8 chunks of
    // 1 KiB (16 rows). Wave w stages chunks {2w, 2w+1} of A and of B.
    // Lane l covers row 16c + (l>>2), u16 col (l&3)*8 -> LDS dest linear.
    const int c0 = wave << 1;
    const int rA = (c0 << 4) + (lane >> 2);
    const int kc = (lane & 3) << 3;
    const u16* gA0 = A  + (arow0 + rA) * K + kc;
    const u16* gA1 = gA0 + (size_t)16 * K;
    const u16* gB0 = Bt + (brow0 + rA) * K + kc;
    const u16* gB1 = gB0 + (size_t)16 * K;
    const int lofs = c0 << 9;   // c0 * 512 u16

    // prologue: stage K-tile 0 into buffer 0
    GL2LDS(gA0, As + lofs); GL2LDS(gA1, As + lofs + 512);
    GL2LDS(gB0, Bs + lofs); GL2LDS(gB1, Bs + lofs + 512);
    __syncthreads();

    int cur = 0;
    for (int k0 = 0; k0 < K; k0 += 32) {
        const int kn = k0 + 32;
        if (kn < K) {   // issue next tile's loads BEFORE compute (overlap)
            const int nb = ((cur ^ 1) << 12) + lofs;
            GL2LDS(gA0 + kn, As + nb); GL2LDS(gA1 + kn, As + nb + 512);
            GL2LDS(gB0 + kn, Bs + nb); GL2LDS(gB1 + kn, Bs + nb + 512);
        }
        const u16* Ab = As + (cur << 12);
        const u16* Bb = Bs + (cur << 12);
        bf16x8 af[4], bf[4];
#pragma unroll
        for (int i = 0; i < 4; ++i)
            af[i] = *(const bf16x8*)(&Ab[(wr + (i << 4) + lm) * 32 + (lq << 3)]);
#pragma unroll
        for (int j = 0; j < 4; ++j)
            bf[j] = *(const bf16x8*)(&Bb[(wc + (j << 4) + lm) * 32 + (lq << 3)]);
#pragma unroll
        for (int i = 0; i < 4; ++i)
#pragma unroll
            for (int j = 0; j < 4; ++j)
                acc[i][j] = __builtin_amdgcn_mfma_f32_16x16x32_bf16(af[i], bf[j], acc[i][j], 0, 0, 0);
        __syncthreads();   // drains vmcnt(0): next tile staged; reads of cur done
        cur ^= 1;
    }

    const bool f32 = (MODE >= 2) ? (*flag != 0) : false;
#pragma unroll
    for (int i = 0; i < 4; ++i) {
#pragma unroll
        for (int rr = 0; rr < 4; ++rr) {
            const int row = (bm << 7) + wr + (i << 4) + (lq << 2) + rr;
            size_t orow;
            if (MODE == 2) {
                int win = row / 49, n = row - win * 49;
                orow = (size_t)win_token(win, n);
            } else {
                orow = (size_t)row;
            }
#pragma unroll
            for (int j = 0; j < 4; ++j) {
                const int col = (bn << 7) + wc + (j << 4) + lm;
                float v = acc[i][j][rr] + bias[col];
                if (MODE == 0) {
                    ((u16*)outv)[(size_t)row * Nn + col] = f2b(v);
                } else if (MODE == 1) {
                    v = 0.5f * v * (1.0f + erff(v * 0.70710678118654752f));
                    ((u16*)outv)[(size_t)row * Nn + col] = f2b(v);
                } else if (MODE == 2) {
                    float res = f32 ? ((const float*)resv)[orow * 512 + col]
                                    : b2f(((const u16*)resv)[orow * 512 + col]);
                    ((u16*)outv)[orow * 512 + col] = f2b(v + res);
                } else {
                    float res = b2f(((const u16*)resv)[(size_t)row * Nn + col]);
                    size_t grow = (size_t)(row + row_off);
                    if (f32) ((float*)outv)[grow * Nn + col] = v + res;
                    else     ((u16*)outv)[grow * Nn + col]  = f2b(v + res);
                }
            }
        }
    }
}

// ---------------- attention: one wave per (window, head) --------------------
__global__ __launch_bounds__(64)
void attn_kernel(const u16* __restrict__ qkv, const float* __restrict__ biasf,
                 const float* __restrict__ amaskf, u16* __restrict__ o, int win_base) {
    const int blk = blockIdx.x;
    const int winl = blk >> 4, head = blk & 15;
    const int wing = win_base + winl;
    const int w = wing & 63;
    const int t = threadIdx.x;
    __shared__ float qf[49 * 32], kf[49 * 32], vf[49 * 32];
    const size_t base = (size_t)winl * 49 * 1536 + head * 32;
    for (int idx = t; idx < 392; idx += 64) {
        int m = idx >> 3, d = (idx & 7) << 2;
        size_t rb = base + (size_t)m * 1536 + d;
        ushort4 uq = *(const ushort4*)(qkv + rb);
        ushort4 uk = *(const ushort4*)(qkv + rb + 512);
        ushort4 uv = *(const ushort4*)(qkv + rb + 1024);
        int o4 = m * 32 + d;
        qf[o4 + 0] = b2f(uq.x); qf[o4 + 1] = b2f(uq.y);
        qf[o4 + 2] = b2f(uq.z); qf[o4 + 3] = b2f(uq.w);
        kf[o4 + 0] = b2f(uk.x); kf[o4 + 1] = b2f(uk.y);
        kf[o4 + 2] = b2f(uk.z); kf[o4 + 3] = b2f(uk.w);
        vf[o4 + 0] = b2f(uv.x); vf[o4 + 1] = b2f(uv.y);
        vf[o4 + 2] = b2f(uv.z); vf[o4 + 3] = b2f(uv.w);
    }
    __syncthreads();
    if (t < 49) {
        float q[32];
#pragma unroll
        for (int d = 0; d < 32; ++d) q[d] = qf[t * 32 + d] * SCALE_ATTN;
        float s[49];
        float mx = -1e30f;
        const float* bp = biasf + head * 2401 + t * 49;
        const float* mp = amaskf + w * 2401 + t * 49;
#pragma unroll
        for (int m = 0; m < 49; ++m) {
            float acc = 0.f;
#pragma unroll
            for (int d = 0; d < 32; ++d) acc += q[d] * kf[m * 32 + d];
            acc += bp[m] + mp[m];
            s[m] = acc;
            mx = fmaxf(mx, acc);
        }
        float sum = 0.f;
#pragma unroll
        for (int m = 0; m < 49; ++m) { s[m] = __expf(s[m] - mx); sum += s[m]; }
        float inv = 1.0f / sum;
        float ov[32];
#pragma unroll
        for (int d = 0; d < 32; ++d) ov[d] = 0.f;
#pragma unroll
        for (int m = 0; m < 49; ++m) {
            float p = s[m];
#pragma unroll
            for (int d = 0; d < 32; ++d) ov[d] += p * vf[m * 32 + d];
        }
        u16* op = o + (size_t)(wing * 49 + t) * 512 + head * 32;
#pragma unroll
        for (int dc = 0; dc < 32; dc += 4) {
            ushort4 pk;
            pk.x = f2b(ov[dc + 0] * inv); pk.y = f2b(ov[dc + 1] * inv);
            pk.z = f2b(ov[dc + 2] * inv); pk.w = f2b(ov[dc + 3] * inv);
            *(ushort4*)(op + dc) = pk;
        }
    }
}

extern "C" void kernel_launch(void* const* d_in, const int* in_sizes, int n_in,
                              void* d_out, int out_size, void* d_ws, size_t ws_size,
                              hipStream_t stream) {
    const void* x      = d_in[0];
    const void* n1g    = d_in[1];
    const void* n1b    = d_in[2];
    const void* qkv_w  = d_in[3];
    const void* qkv_b  = d_in[4];
    const void* relt   = d_in[5];
    const void* proj_w = d_in[6];
    const void* proj_b = d_in[7];
    const void* n2g    = d_in[8];
    const void* n2b    = d_in[9];
    const void* fc1_w  = d_in[10];
    const void* fc1_b  = d_in[11];
    const void* fc2_w  = d_in[12];
    const void* fc2_b  = d_in[13];
    const int*  ridx   = (const int*)d_in[14];
    const void* amask  = d_in[15];

    char* ws = (char*)d_ws;
    u16*  wT_qkv  = (u16*)(ws);                       // 1536x512 bf16
    u16*  wT_proj = (u16*)(ws + 1572864);             // 512x512
    u16*  wT_fc1  = (u16*)(ws + 2097152);             // 2048x512
    u16*  wT_fc2  = (u16*)(ws + 4194304);             // 512x2048 -> ends 6,291,456
    float* biasf  = (float*)(ws + 6291456);           // 16*2401 -> ends 6,445,120
    float* amaskf = (float*)(ws + 6445120);           // 64*2401 -> ends 7,059,776
    float* qkv_bf = (float*)(ws + 7059776);           // 1536
    float* proj_bf= (float*)(ws + 7065920);           // 512
    float* fc1_bf = (float*)(ws + 7067968);           // 2048
    float* fc2_bf = (float*)(ws + 7076160);           // 512
    float* n1gf   = (float*)(ws + 7078208);           // 512
    float* n1bf   = (float*)(ws + 7080256);           // 512
    float* n2gf   = (float*)(ws + 7082304);           // 512
    float* n2bf   = (float*)(ws + 7084352);           // 512
    float* reltf  = (float*)(ws + 7086400);           // 169*16 -> ends 7,097,216
    int*   flag   = (int*)(ws + 7097216);
    u16* bufA = (u16*)(ws + 8388608);                 // 102,760,448 B : wins -> y
    u16* bufB = (u16*)(ws + 8388608 + 102760448);     //  77,070,336 B : qkv chunk -> m1 chunk
    u16* bufC = (u16*)(ws + 8388608 + 102760448 + 77070336); // 102,760,448 B : o -> h2
    // peak ws usage = 290,979,840 B

    detect_flag<<<1, 64, 0, stream>>>((const unsigned int*)n1g, flag);

    conv_f32<<<6, 256, 0, stream>>>(qkv_b, qkv_bf, 1536, flag);
    conv_f32<<<2, 256, 0, stream>>>(proj_b, proj_bf, 512, flag);
    conv_f32<<<8, 256, 0, stream>>>(fc1_b, fc1_bf, 2048, flag);
    conv_f32<<<2, 256, 0, stream>>>(fc2_b, fc2_bf, 512, flag);
    conv_f32<<<2, 256, 0, stream>>>(n1g, n1gf, 512, flag);
    conv_f32<<<2, 256, 0, stream>>>(n1b, n1bf, 512, flag);
    conv_f32<<<2, 256, 0, stream>>>(n2g, n2gf, 512, flag);
    conv_f32<<<2, 256, 0, stream>>>(n2b, n2bf, 512, flag);
    conv_f32<<<11, 256, 0, stream>>>(relt, reltf, 169 * 16, flag);
    conv_f32<<<(64 * 2401 + 255) / 256, 256, 0, stream>>>(amask, amaskf, 64 * 2401, flag);

    transpose_k<<<dim3(48, 16), 256, 0, stream>>>(qkv_w, wT_qkv, 512, 1536, flag);
    transpose_k<<<dim3(16, 16), 256, 0, stream>>>(proj_w, wT_proj, 512, 512, flag);
    transpose_k<<<dim3(64, 16), 256, 0, stream>>>(fc1_w, wT_fc1, 512, 2048, flag);
    transpose_k<<<dim3(16, 64), 256, 0, stream>>>(fc2_w, wT_fc2, 2048, 512, flag);
    bias_expand<<<(16 * 2401 + 255) / 256, 256, 0, stream>>>(reltf, ridx, biasf);

    // LN1 + roll + window partition -> wins (bufA)
    ln_kernel<true><<<MROWS, 256, 0, stream>>>(x, n1gf, n1bf, bufA, flag);

    // QKV + attention in 4 window-chunks of 512 windows (25088 rows)
    for (int c = 0; c < 4; ++c) {
        const u16* Ain = bufA + (size_t)c * 25088 * 512;
        gemm128<0><<<196 * 12, 256, 0, stream>>>(Ain, wT_qkv, qkv_bf, 512, 1536, 12, bufB, nullptr, flag, 0);
        attn_kernel<<<512 * 16, 64, 0, stream>>>(bufB, biasf, amaskf, bufC, c * 512);
    }

    // proj + window reverse + roll + x residual -> y (bufA, bf16)
    gemm128<2><<<784 * 4, 256, 0, stream>>>(bufC, wT_proj, proj_bf, 512, 512, 4, bufA, x, flag, 0);

    // LN2 -> h2 (bufC)
    ln_kernel<false><<<MROWS, 256, 0, stream>>>(bufA, n2gf, n2bf, bufC, flag);

    // MLP in row-chunks of 16384 (m1 chunk in bufB: 16384*2048*2 = 67.1 MB)
    for (int mc0 = 0; mc0 < MROWS; mc0 += 16384) {
        int rows = (MROWS - mc0 < 16384) ? (MROWS - mc0) : 16384;
        int tiles = rows >> 7;
        gemm128<1><<<tiles * 16, 256, 0, stream>>>(bufC + (size_t)mc0 * 512, wT_fc1, fc1_bf, 512, 2048, 16, bufB, nullptr, flag, 0);
        gemm128<3><<<tiles * 4, 256, 0, stream>>>(bufB, wT_fc2, fc2_bf, 2048, 512, 4, d_out, bufA + (size_t)mc0 * 512, flag, mc0);
    }
}